// Round 2
// baseline (44.077 us; speedup 1.0000x reference)
//
#include <hip/hip_runtime.h>
#include <math.h>

#define PI_F 3.14159265358979323846f
#define LSTR 266   // 256 + 10; stride%32 == 10 -> ~2-way bank aliasing (free)

__device__ __forceinline__ float red16(float v) {
  v += __shfl_xor(v, 1);
  v += __shfl_xor(v, 2);
  v += __shfl_xor(v, 4);
  v += __shfl_xor(v, 8);
  return v;
}

// Kernel 1: Zernike pooling. One block per (batch, rank): 32 channels x 256 pixels.
__global__ __launch_bounds__(256) void zpool_kernel(const float* __restrict__ x,
                                                    float* __restrict__ pooled) {
  const int blk = blockIdx.x;              // 0..3071
  const int b = blk / 3;
  const int rank = blk - b * 3;
  const float* __restrict__ src = x + (size_t)b * 24576 + rank * 32;

  __shared__ float lds[32 * LSTR];
  const int t = threadIdx.x;

  // Stage tile: 256 rows x 32 ch. float4 global loads (full 64B lines),
  // 4 scalar LDS writes each (transpose to channel-major).
#pragma unroll
  for (int i = 0; i < 8; ++i) {
    const int idx = t + i * 256;           // 0..2047
    const int p = idx >> 3;                // pixel 0..255
    const int c4 = (idx & 7) * 4;          // channel base 0..28
    const float4 v = *reinterpret_cast<const float4*>(src + p * 96 + c4);
    lds[(c4 + 0) * LSTR + p] = v.x;
    lds[(c4 + 1) * LSTR + p] = v.y;
    lds[(c4 + 2) * LSTR + p] = v.z;
    lds[(c4 + 3) * LSTR + p] = v.w;
  }
  __syncthreads();

  const int lane = t & 63;
  const int w = t >> 6;                    // wave 0..3
  const int sub = lane >> 4;               // channel subgroup 0..3
  const int sl = lane & 15;                // pixel column (w-coord)
  const float X = -1.0f + (float)sl * (2.0f / 15.0f);   // lane-constant

#pragma unroll
  for (int g = 0; g < 2; ++g) {
    const int ch = w * 8 + g * 4 + sub;    // 0..31
    const float* base = &lds[ch * LSTR + sl];
    float f[16];
#pragma unroll
    for (int k = 0; k < 16; ++k) f[k] = base[16 * k];   // pixel p = sl + 16k

    // Pass 1: centroid sums. X constant per lane -> sx = X * s0.
    float s0 = 0.0f, sy = 0.0f;
#pragma unroll
    for (int k = 0; k < 16; ++k) {
      const float Y = -1.0f + (float)k * (2.0f / 15.0f);
      s0 += f[k];
      sy = fmaf(f[k], Y, sy);
    }
    float sx = X * s0;
    s0 = red16(s0); sx = red16(sx); sy = red16(sy);
    const float invm = 1.0f / (s0 + 1e-6f);
    const float cx = sx * invm;
    const float cy = sy * invm;

    const float Xs = X - cx;
    const float Xs2 = Xs * Xs;
    const float twoXs = Xs + Xs;
    const float thXs2 = 3.0f * Xs2;

    // Pass 2: polynomial moment accumulators (re/im pairs, im sign dropped).
    float a0 = 0, a1 = 0, b1 = 0, a2 = 0, a3 = 0, b3 = 0, a4 = 0, b4 = 0, a5 = 0, b5 = 0;
#pragma unroll
    for (int k = 0; k < 16; ++k) {
      const float Y = -1.0f + (float)k * (2.0f / 15.0f);
      const float Ys = Y - cy;
      const float Ys2 = Ys * Ys;
      const float r2 = Xs2 + Ys2 + 1e-12f;
      const float gv = (r2 <= 1.0f) ? f[k] : 0.0f;   // unit-disk mask
      const float gx = gv * Xs;
      const float gy = gv * Ys;
      a0 += gv;
      a1 += gx;
      b1 += gy;
      a2 = fmaf(gv, fmaf(2.0f, r2, -1.0f), a2);
      a3 = fmaf(gv, Xs2 - Ys2, a3);
      b3 = fmaf(gy, twoXs, b3);
      const float t31 = fmaf(3.0f, r2, -2.0f);
      a4 = fmaf(gx, t31, a4);
      b4 = fmaf(gy, t31, b4);
      a5 = fmaf(gx, fmaf(-3.0f, Ys2, Xs2), a5);
      b5 = fmaf(gy, thXs2 - Ys2, b5);
    }
    a0 = red16(a0); a1 = red16(a1); b1 = red16(b1); a2 = red16(a2); a3 = red16(a3);
    b3 = red16(b3); a4 = red16(a4); b4 = red16(b4); a5 = red16(a5); b5 = red16(b5);

    if (sl == 0) {
      float* po = pooled + (size_t)b * 576 + rank * 192 + ch;
      const float INV = 1.0f / 65536.0f;    // (1/256)^2 for the means
      po[0]   = (1.0f / PI_F) * sqrtf(a0 * a0 * INV + 1e-12f);
      po[32]  = (2.0f / PI_F) * sqrtf(fmaf(a1, a1, b1 * b1) * INV + 1e-12f);
      po[64]  = (3.0f / PI_F) * sqrtf(a2 * a2 * INV + 1e-12f);
      po[96]  = (3.0f / PI_F) * sqrtf(fmaf(a3, a3, b3 * b3) * INV + 1e-12f);
      po[128] = (4.0f / PI_F) * sqrtf(fmaf(a4, a4, b4 * b4) * INV + 1e-12f);
      po[160] = (4.0f / PI_F) * sqrtf(fmaf(a5, a5, b5 * b5) * INV + 1e-12f);
    }
  }
}

// Kernel 2: batch-norm stats per feature; fold into scale a and shift c.
__global__ __launch_bounds__(256) void bn_stats_kernel(const float* __restrict__ pooled,
                                                       const float* __restrict__ gamma,
                                                       const float* __restrict__ beta,
                                                       float* __restrict__ a,
                                                       float* __restrict__ c) {
  const int f = blockIdx.x;   // 0..575
  const int t = threadIdx.x;  // 256
  float s = 0.0f, sq = 0.0f;
#pragma unroll
  for (int j = 0; j < 4; ++j) {
    const float v = pooled[(size_t)(t + 256 * j) * 576 + f];
    s += v;
    sq = fmaf(v, v, sq);
  }
#pragma unroll
  for (int m = 1; m < 64; m <<= 1) {
    s += __shfl_xor(s, m);
    sq += __shfl_xor(sq, m);
  }
  __shared__ float ls[8];
  const int w = t >> 6;
  if ((t & 63) == 0) { ls[w * 2] = s; ls[w * 2 + 1] = sq; }
  __syncthreads();
  if (t == 0) {
    s = ls[0] + ls[2] + ls[4] + ls[6];
    sq = ls[1] + ls[3] + ls[5] + ls[7];
    const float mean = s * (1.0f / 1024.0f);
    const float var = fmaf(-mean, mean, sq * (1.0f / 1024.0f));  // biased var
    const float istd = rsqrtf(var + 1e-5f);
    const float av = gamma[f] * istd;
    a[f] = av;
    c[f] = fmaf(-mean, av, beta[f]);
  }
}

// Kernel 3: z = pooled*a + c, then z @ W^T + b. One wave per batch row.
__global__ __launch_bounds__(64) void head_kernel(const float* __restrict__ pooled,
                                                  const float* __restrict__ a,
                                                  const float* __restrict__ c,
                                                  const float* __restrict__ Wl,
                                                  const float* __restrict__ bl,
                                                  float* __restrict__ out) {
  const int row = blockIdx.x;     // 0..1023
  const int lane = threadIdx.x;   // 0..63
  const float* pr = pooled + (size_t)row * 576;
  float acc0 = 0, acc1 = 0, acc2 = 0, acc3 = 0, acc4 = 0;
  float acc5 = 0, acc6 = 0, acc7 = 0, acc8 = 0, acc9 = 0;
#pragma unroll
  for (int j = 0; j < 9; ++j) {
    const int k = lane + 64 * j;
    const float z = fmaf(pr[k], a[k], c[k]);
    acc0 = fmaf(z, Wl[0 * 576 + k], acc0);
    acc1 = fmaf(z, Wl[1 * 576 + k], acc1);
    acc2 = fmaf(z, Wl[2 * 576 + k], acc2);
    acc3 = fmaf(z, Wl[3 * 576 + k], acc3);
    acc4 = fmaf(z, Wl[4 * 576 + k], acc4);
    acc5 = fmaf(z, Wl[5 * 576 + k], acc5);
    acc6 = fmaf(z, Wl[6 * 576 + k], acc6);
    acc7 = fmaf(z, Wl[7 * 576 + k], acc7);
    acc8 = fmaf(z, Wl[8 * 576 + k], acc8);
    acc9 = fmaf(z, Wl[9 * 576 + k], acc9);
  }
#pragma unroll
  for (int m = 1; m < 64; m <<= 1) {
    acc0 += __shfl_xor(acc0, m); acc1 += __shfl_xor(acc1, m);
    acc2 += __shfl_xor(acc2, m); acc3 += __shfl_xor(acc3, m);
    acc4 += __shfl_xor(acc4, m); acc5 += __shfl_xor(acc5, m);
    acc6 += __shfl_xor(acc6, m); acc7 += __shfl_xor(acc7, m);
    acc8 += __shfl_xor(acc8, m); acc9 += __shfl_xor(acc9, m);
  }
  if (lane == 0) {
    float* o = out + (size_t)row * 10;
    o[0] = acc0 + bl[0]; o[1] = acc1 + bl[1]; o[2] = acc2 + bl[2];
    o[3] = acc3 + bl[3]; o[4] = acc4 + bl[4]; o[5] = acc5 + bl[5];
    o[6] = acc6 + bl[6]; o[7] = acc7 + bl[7]; o[8] = acc8 + bl[8];
    o[9] = acc9 + bl[9];
  }
}

extern "C" void kernel_launch(void* const* d_in, const int* in_sizes, int n_in,
                              void* d_out, int out_size, void* d_ws, size_t ws_size,
                              hipStream_t stream) {
  const float* x     = (const float*)d_in[0];
  const float* gamma = (const float*)d_in[1];
  const float* beta  = (const float*)d_in[2];
  const float* Wl    = (const float*)d_in[3];
  const float* bl    = (const float*)d_in[4];
  float* out = (float*)d_out;

  float* pooled = (float*)d_ws;            // 1024*576 floats
  float* a = pooled + 576 * 1024;          // 576 floats
  float* c = a + 576;                      // 576 floats

  zpool_kernel<<<3072, 256, 0, stream>>>(x, pooled);
  bn_stats_kernel<<<576, 256, 0, stream>>>(pooled, gamma, beta, a, c);
  head_kernel<<<1024, 64, 0, stream>>>(pooled, a, c, Wl, bl, out);
}